// Round 15
// baseline (235.938 us; speedup 1.0000x reference)
//
#include <hip/hip_runtime.h>

#define DEVI __device__ __forceinline__

typedef _Float16 f16x8 __attribute__((ext_vector_type(8)));
typedef _Float16 f16x4v __attribute__((ext_vector_type(4)));
typedef _Float16 f16x2 __attribute__((ext_vector_type(2)));
typedef __fp16 fp16x2 __attribute__((ext_vector_type(2)));
typedef float f32x4 __attribute__((ext_vector_type(4)));
typedef float f32x16 __attribute__((ext_vector_type(16)));
typedef unsigned u32x4 __attribute__((ext_vector_type(4)));

DEVI void gl16(const void* g, void* l) {
  __builtin_amdgcn_global_load_lds((const __attribute__((address_space(1))) void*)g,
                                   (__attribute__((address_space(3))) void*)l, 16, 0, 0);
}

#define VMCNT(N) asm volatile("s_waitcnt vmcnt(" #N ")" ::: "memory")
#define LGKM0() asm volatile("s_waitcnt lgkmcnt(0)" ::: "memory")
#define BARRIER() asm volatile("s_barrier" ::: "memory")

#if __has_builtin(__builtin_amdgcn_exp2f)
#define EXP2(x) __builtin_amdgcn_exp2f(x)
#else
#define EXP2(x) exp2f(x)
#endif

DEVI unsigned pk2(float a, float b) {
  fp16x2 t = __builtin_amdgcn_cvt_pkrtz(a, b);
  return __builtin_bit_cast(unsigned, t);
}
DEVI void pl32swap(unsigned &a, unsigned &b) {
  asm volatile("v_permlane32_swap_b32 %0, %1" : "+v"(a), "+v"(b));
}
DEVI float max3f(float a, float b, float c) {
  float d;
  asm("v_max3_f32 %0, %1, %2, %3" : "=v"(d) : "v"(a), "v"(b), "v"(c));
  return d;
}

// ---------------- fused prep: x f32->f16 + both weight transposes ----------------
// w_inT columns are PERMUTED: new col = reg*1280 + head*80 + d  (reg 0=q,1=k,2=v)
__global__ __launch_bounds__(256) void k_prep(const float* __restrict__ x, _Float16* __restrict__ xb,
                                              const float* __restrict__ w_in, _Float16* __restrict__ w_inT,
                                              const float* __restrict__ w_out, _Float16* __restrict__ w_outT) {
  __shared__ float t[32][33];
  int bid = blockIdx.x;
  int tid = threadIdx.x;
  if (bid < 2048) {
    const int n4 = 8192 * 1280 / 4;
    for (int i = bid * 256 + tid; i < n4; i += 2048 * 256) {
      float4 v = ((const float4*)x)[i];
      f16x4v h = { (_Float16)v.x, (_Float16)v.y, (_Float16)v.z, (_Float16)v.w };
      ((f16x4v*)xb)[i] = h;
    }
    return;
  }
  const float* in; _Float16* out; int R, C, tIdx; bool perm;
  if (bid < 6848) { in = w_in;  out = w_inT;  R = 1280; C = 3840; tIdx = bid - 2048; perm = true; }
  else            { in = w_out; out = w_outT; R = 1280; C = 1280; tIdx = bid - 6848; perm = false; }
  int ntc = C / 32;
  int cb = (tIdx % ntc) * 32, rb = (tIdx / ntc) * 32;
  int tx = tid & 31, ty = tid >> 5;
  #pragma unroll
  for (int i = ty; i < 32; i += 8) t[i][tx] = in[(size_t)(rb + i) * C + cb + tx];
  __syncthreads();
  #pragma unroll
  for (int i = ty; i < 32; i += 8) {
    int c = cb + i;
    if (perm) {
      int hq = c / 240, tt = c - hq * 240;
      int reg = tt / 80, d = tt - reg * 80;
      c = reg * 1280 + hq * 80 + d;
    }
    out[(size_t)c * R + rb + tx] = (_Float16)t[tx][i];
  }
}

// ================= 256x256 4-phase GEMM (qkv producer), permuted-N, row-major epilogue ========
// Race-free merged schedule: each phase's stage-parity is disjoint from its read-parity.
// M1: read(T0,k1)[p0]            | MM(T0,k0)
// M2: stage S0[p0]; VMCNT(8);bar | read(T1,k0)[p1]; MM(T0,k1)
// M3: read(T1,k1)[p1]            | MM(T1,k0)
// M4: stage S1[p1]; VMCNT(8);bar | read(S0,k0)[p0]; MM(T1,k1)

#define MM(NLO, AF, BF) do {                                                                       \
    __builtin_amdgcn_s_setprio(1);                                                                 \
    _Pragma("unroll")                                                                              \
    for (int m_ = 0; m_ < 8; m_++) {                                                               \
      acc[m_][NLO]     = __builtin_amdgcn_mfma_f32_16x16x32_f16(AF[m_], BF[NLO],     acc[m_][NLO],     0, 0, 0); \
      acc[m_][NLO + 1] = __builtin_amdgcn_mfma_f32_16x16x32_f16(AF[m_], BF[NLO + 1], acc[m_][NLO + 1], 0, 0, 0); \
    }                                                                                              \
    __builtin_amdgcn_s_setprio(0);                                                                 \
  } while (0)

#define LDA(KT, KK, DST) do {                                                                      \
    const _Float16* bas_ = &smem[(size_t)((((KT) & 1) * 2) + wr) * 8192];                          \
    _Pragma("unroll")                                                                              \
    for (int m_ = 0; m_ < 8; m_++)                                                                 \
      DST[m_] = *(const f16x8*)&bas_[(m_ * 16 + ln) * 64 + (((((KK) * 4) + g) ^ chB) << 3)];       \
  } while (0)

#define LDB(KT, KK, DST) do {                                                                      \
    const _Float16* bas_ = &smem[32768 + (size_t)((((KT) & 1) * 2) + (wc >> 1)) * 8192];           \
    _Pragma("unroll")                                                                              \
    for (int n_ = 0; n_ < 4; n_++)                                                                 \
      DST[n_] = *(const f16x8*)&bas_[((wc & 1) * 64 + n_ * 16 + ln) * 64 + (((((KK) * 4) + g) ^ chB) << 3)]; \
  } while (0)

template<int M, int N, int K>
__global__ __launch_bounds__(512, 2) void k_gemm8(const _Float16* __restrict__ A, const _Float16* __restrict__ BT,
                                                  const float* __restrict__ bias,
                                                  _Float16* __restrict__ qo, _Float16* __restrict__ ko,
                                                  _Float16* __restrict__ vo) {
  extern __shared__ _Float16 smem[];
  constexpr int NT = K / 64;
  constexpr int NI = NT / 2;
  const int tid = threadIdx.x;
  const int w = tid >> 6, lane = tid & 63, ln = lane & 15, g = lane >> 4;
  const int wr = w >> 2, wc = w & 3;
  const int l8 = lane >> 3, l7 = lane & 7;
  const int stChunk = (l7 ^ l8) << 3;
  const int chB = ln & 7;

  constexpr int MT = M / 256;
  const int xcd = blockIdx.x & 7;
  const int i = blockIdx.x >> 3;
  const int bm0 = (xcd * (MT / 8) + (i & 3)) * 256;
  const int bn0 = (i >> 2) * 256;

  auto stgA = [&](int kt, int hh) {
    _Float16* ldsb = &smem[(size_t)((kt & 1) * 2 + hh) * 8192 + w * 1024];
    const _Float16* g0 = &A[(size_t)(bm0 + hh * 128 + w * 16 + l8) * K + kt * 64 + stChunk];
    gl16(g0, ldsb);
    gl16(g0 + (size_t)8 * K, ldsb + 512);
  };
  auto stgB = [&](int kt, int hh) {
    _Float16* ldsb = &smem[32768 + (size_t)((kt & 1) * 2 + hh) * 8192 + w * 1024];
    const _Float16* g0 = &BT[(size_t)(bn0 + hh * 128 + w * 16 + l8) * K + kt * 64 + stChunk];
    gl16(g0, ldsb);
    gl16(g0 + (size_t)8 * K, ldsb + 512);
  };

  f32x4 acc[8][4] = {};
  f16x8 a0[8], a1[8], b0[4], b1[4];

  // prologue: T0 fully (8 gl16), T1 fully (8 gl16); drain T0's; read (T0,kk0)
  stgA(0, 0); stgA(0, 1); stgB(0, 0); stgB(0, 1);
  stgA(1, 0); stgA(1, 1); stgB(1, 0); stgB(1, 1);
  VMCNT(8);
  BARRIER();
  LDA(0, 0, a0); LDB(0, 0, b0);

  for (int it = 0; it < NI; ++it) {
    const int T0 = 2 * it, T1 = 2 * it + 1;
    const int S0 = (T0 + 2 < NT) ? T0 + 2 : 0;  // wrapped tail stages never consumed
    const int S1 = (T1 + 2 < NT) ? T1 + 2 : 1;
    // M1: read (T0,k1) [p0]; MM (T0,k0)
    LDB(T0, 1, b1); LDA(T0, 1, a1);
    BARRIER();
    MM(0, a0, b0); MM(2, a0, b0);
    LGKM0(); BARRIER();
    // M2: stage S0 [p0]; drain T1's stages; read (T1,k0) [p1]; MM (T0,k1)
    stgA(S0, 0); stgA(S0, 1); stgB(S0, 0); stgB(S0, 1);
    VMCNT(8);
    BARRIER();
    LDA(T1, 0, a0); LDB(T1, 0, b0);
    MM(0, a1, b1); MM(2, a1, b1);
    LGKM0(); BARRIER();
    // M3: read (T1,k1) [p1]; MM (T1,k0)
    LDB(T1, 1, b1); LDA(T1, 1, a1);
    BARRIER();
    MM(0, a0, b0); MM(2, a0, b0);
    LGKM0(); BARRIER();
    // M4: stage S1 [p1]; drain S0's stages; read (S0,k0) [p0]; MM (T1,k1)
    stgA(S1, 0); stgA(S1, 1); stgB(S1, 0); stgB(S1, 1);
    VMCNT(8);
    BARRIER();
    LDA(S0, 0, a0); LDB(S0, 0, b0);
    MM(0, a1, b1); MM(2, a1, b1);
    LGKM0(); BARRIER();
  }

  // ---- epilogue: acc -> LDS f16 [256][256]; tile purely q, k, or v; row-major stores ----
  VMCNT(0);
  BARRIER();
  _Float16* sH = smem;
  const int regn = bn0 / 1280;   // 0=q, 1=k, 2=v
  const int relb = bn0 - regn * 1280;
  #pragma unroll
  for (int n = 0; n < 4; n++) {
    int col = wc * 64 + n * 16 + ln;
    int rel = relb + col;
    int h = rel / 80, d = rel - h * 80;
    float bv = bias[h * 240 + regn * 80 + d];
    float scl = (regn == 0) ? (0.11180339887498948f * 1.4426950408889634f) : 1.0f;
    #pragma unroll
    for (int m = 0; m < 8; m++) {
      #pragma unroll
      for (int r = 0; r < 4; r++) {
        int row = wr * 128 + m * 16 + 4 * g + r;
        sH[row * 256 + col] = (_Float16)((acc[m][n][r] + bv) * scl);
      }
    }
  }
  LGKM0();
  BARRIER();
  _Float16* dst = (regn == 0) ? qo : (regn == 1) ? ko : vo;   // all [head][1024][80]
  #pragma unroll
  for (int i2 = 0; i2 < 16; i2++) {
    int id = tid + 512 * i2;
    int row = id >> 5, c8 = id & 31;
    f16x8 v = *(const f16x8*)&sH[row * 256 + c8 * 8];
    int rel = relb + c8 * 8;
    int h = rel / 80, d0 = rel - h * 80;
    int grow = bm0 + row;
    *(f16x8*)&dst[(size_t)(((grow & 7) * 16 + h) * 1024 + (grow >> 3)) * 80 + d0] = v;
  }
}

// ================= 128x256 4-phase GEMM (out_proj): C[M,N] f32 = A*BT^T + bias =================
// Same race-free merged schedule; A is one half-group (2 gl16), B two (4 gl16) -> groups of 6.

#define MMo(NLO, AF, BF) do {                                                                      \
    __builtin_amdgcn_s_setprio(1);                                                                 \
    _Pragma("unroll")                                                                              \
    for (int m_ = 0; m_ < 4; m_++) {                                                               \
      acc[m_][NLO]     = __builtin_amdgcn_mfma_f32_16x16x32_f16(AF[m_], BF[NLO],     acc[m_][NLO],     0, 0, 0); \
      acc[m_][NLO + 1] = __builtin_amdgcn_mfma_f32_16x16x32_f16(AF[m_], BF[NLO + 1], acc[m_][NLO + 1], 0, 0, 0); \
    }                                                                                              \
    __builtin_amdgcn_s_setprio(0);                                                                 \
  } while (0)

#define LDAo(KT, KK, DST) do {                                                                     \
    const _Float16* bas_ = &smem[(size_t)((KT) & 1) * 8192];                                       \
    _Pragma("unroll")                                                                              \
    for (int m_ = 0; m_ < 4; m_++)                                                                 \
      DST[m_] = *(const f16x8*)&bas_[(wr * 64 + m_ * 16 + ln) * 64 + (((((KK) * 4) + g) ^ chB) << 3)]; \
  } while (0)

#define LDBo(KT, KK, DST) do {                                                                     \
    const _Float16* bas_ = &smem[16384 + (size_t)(((KT) & 1) * 2 + (wc >> 1)) * 8192];             \
    _Pragma("unroll")                                                                              \
    for (int n_ = 0; n_ < 4; n_++)                                                                 \
      DST[n_] = *(const f16x8*)&bas_[((wc & 1) * 64 + n_ * 16 + ln) * 64 + (((((KK) * 4) + g) ^ chB) << 3)]; \
  } while (0)

template<int M, int N, int K>
__global__ __launch_bounds__(512, 2) void k_gemm8o(const _Float16* __restrict__ A, const _Float16* __restrict__ BT,
                                                   const float* __restrict__ bias, float* __restrict__ outF) {
  extern __shared__ _Float16 smem[];
  constexpr int NT = K / 64;     // 20
  constexpr int NI = NT / 2;     // 10
  const int tid = threadIdx.x;
  const int w = tid >> 6, lane = tid & 63, ln = lane & 15, g = lane >> 4;
  const int wr = w >> 2, wc = w & 3;
  const int l8 = lane >> 3, l7 = lane & 7;
  const int stChunk = (l7 ^ l8) << 3;
  const int chB = ln & 7;

  const int xcd = blockIdx.x & 7;
  const int i = blockIdx.x >> 3;            // 0..39
  const int bm0 = (xcd * 8 + (i & 7)) * 128;
  const int bn0 = (i >> 3) * 256;

  auto stgA = [&](int kt) {
    _Float16* ldsb = &smem[(size_t)(kt & 1) * 8192 + w * 1024];
    const _Float16* g0 = &A[(size_t)(bm0 + w * 16 + l8) * K + kt * 64 + stChunk];
    gl16(g0, ldsb);
    gl16(g0 + (size_t)8 * K, ldsb + 512);
  };
  auto stgB = [&](int kt, int hh) {
    _Float16* ldsb = &smem[16384 + (size_t)((kt & 1) * 2 + hh) * 8192 + w * 1024];
    const _Float16* g0 = &BT[(size_t)(bn0 + hh * 128 + w * 16 + l8) * K + kt * 64 + stChunk];
    gl16(g0, ldsb);
    gl16(g0 + (size_t)8 * K, ldsb + 512);
  };

  f32x4 acc[4][4] = {};
  f16x8 a0[4], a1[4], b0[4], b1[4];

  // prologue: T0 (6 gl16), T1 (6 gl16); drain T0's; read (T0,kk0)
  stgA(0); stgB(0, 0); stgB(0, 1);
  stgA(1); stgB(1, 0); stgB(1, 1);
  VMCNT(6);
  BARRIER();
  LDAo(0, 0, a0); LDBo(0, 0, b0);

  for (int it = 0; it < NI; ++it) {
    const int T0 = 2 * it, T1 = 2 * it + 1;
    const int S0 = (T0 + 2 < NT) ? T0 + 2 : 0;
    const int S1 = (T1 + 2 < NT) ? T1 + 2 : 1;
    // M1
    LDBo(T0, 1, b1); LDAo(T0, 1, a1);
    BARRIER();
    MMo(0, a0, b0); MMo(2, a0, b0);
    LGKM0(); BARRIER();
    // M2: stage S0 [p0]; drain T1's; read (T1,k0) [p1]
    stgA(S0); stgB(S0, 0); stgB(S0, 1);
    VMCNT(6);
    BARRIER();
    LDAo(T1, 0, a0); LDBo(T1, 0, b0);
    MMo(0, a1, b1); MMo(2, a1, b1);
    LGKM0(); BARRIER();
    // M3
    LDBo(T1, 1, b1); LDAo(T1, 1, a1);
    BARRIER();
    MMo(0, a0, b0); MMo(2, a0, b0);
    LGKM0(); BARRIER();
    // M4: stage S1 [p1]; drain S0's; read (S0,k0) [p0]
    stgA(S1); stgB(S1, 0); stgB(S1, 1);
    VMCNT(6);
    BARRIER();
    LDAo(S0, 0, a0); LDBo(S0, 0, b0);
    MMo(0, a1, b1); MMo(2, a1, b1);
    LGKM0(); BARRIER();
  }

  VMCNT(0);
  #pragma unroll
  for (int n = 0; n < 4; n++) {
    int col = bn0 + wc * 64 + n * 16 + ln;
    float bv = bias[col];
    #pragma unroll
    for (int m = 0; m < 4; m++) {
      int rbase = bm0 + wr * 64 + m * 16 + 4 * g;
      #pragma unroll
      for (int r = 0; r < 4; r++)
        outF[(size_t)(rbase + r) * N + col] = acc[m][n][r] + bv;
    }
  }
}

// ---------------- flash attention: QBLK=256, 8 waves x 32 q-rows, in-register softmax ----------------
// qb/kb/vb: [head][1024][80] f16 (q pre-scaled by log2e/sqrt(80)); V transposed during staging
// via quad-chunks + b64 writes. V^T row 80 = ones -> ct[2][8] accumulates the softmax denominator.
__global__ __launch_bounds__(512, 2) void k_attn(const _Float16* __restrict__ qb, const _Float16* __restrict__ kb,
                                                 const _Float16* __restrict__ vb, _Float16* __restrict__ ctxg) {
  extern __shared__ _Float16 smem[];
  _Float16* Kb0 = smem;                    // [64][128] swizzled
  _Float16* Kb1 = smem + 8192;
  _Float16* Vb0 = smem + 16384;            // [96][64] swizzled; rows 81..95 garbage (ignored)
  _Float16* Vb1 = smem + 16384 + 6144;

  const int tid = threadIdx.x;
  const int w = tid >> 6, lane = tid & 63;
  const int l32 = lane & 31, h = lane >> 5;
  const int lx = l32 & 7;
  const int xcd = blockIdx.x & 7;
  const int j = blockIdx.x >> 3;
  const int head = xcd + 8 * (j & 15);
  const int s0 = (j >> 4) * 256;
  const int bb = head >> 4, h16 = head & 15;
  const size_t hbase = (size_t)head * 81920;

  const int cA = tid;
  const int cB = (tid < 128) ? tid + 512 : tid;
  const int sA = cA & 63, dA = cA >> 6;
  const int sB = cB & 63, dB = cB >> 6;
  const _Float16* kGA = kb + hbase + sA * 80 + dA * 8;
  const _Float16* kGB = kb + hbase + sB * 80 + dB * 8;
  const int kOA = sA * 128 + ((dA ^ (sA & 7)) << 3);
  const int kOB = sB * 128 + ((dB ^ (sB & 7)) << 3);

  const int s4 = tid & 15, dc = tid >> 4;
  const _Float16* vG = vb + hbase + (s4 * 4) * 80 + dc * 8;

  uint4 krA, krB, vq0, vq1, vq2, vq3;
  auto issue = [&](int kt) {
    krA = *(const uint4*)(kGA + kt * 5120);
    krB = *(const uint4*)(kGB + kt * 5120);
    if (tid < 160) {
      const _Float16* p = vG + kt * 5120;
      vq0 = *(const uint4*)(p);
      vq1 = *(const uint4*)(p + 80);
      vq2 = *(const uint4*)(p + 160);
      vq3 = *(const uint4*)(p + 240);
    }
  };
  auto stage = [&](int b) {
    _Float16* kd = b ? Kb1 : Kb0;
    _Float16* vd = b ? Vb1 : Vb0;
    *(uint4*)(kd + kOA) = krA;
    *(uint4*)(kd + kOB) = krB;
    if (tid < 160) {
      const unsigned* w0 = (const unsigned*)&vq0;
      const unsigned* w1 = (const unsigned*)&vq1;
      const unsigned* w2 = (const unsigned*)&vq2;
      const unsigned* w3 = (const unsigned*)&vq3;
      #pragma unroll
      for (int jj = 0; jj < 8; ++jj) {
        int jw = jj >> 1;
        unsigned lo, hi;
        if (jj & 1) {
          lo = (w0[jw] >> 16) | (w1[jw] & 0xffff0000u);
          hi = (w2[jw] >> 16) | (w3[jw] & 0xffff0000u);
        } else {
          lo = (w0[jw] & 0xffffu) | (w1[jw] << 16);
          hi = (w2[jw] & 0xffffu) | (w3[jw] << 16);
        }
        unsigned long long u = (unsigned long long)lo | ((unsigned long long)hi << 32);
        int d = dc * 8 + jj;
        *(unsigned long long*)(vd + d * 64 + (((s4 >> 1) ^ jj) << 3) + ((s4 & 1) << 2)) = u;
      }
    }
  };

  const int qrow = s0 + w * 32 + l32;
  f16x8 qf[5];
  #pragma unroll
  for (int s = 0; s < 5; s++)
    qf[s] = *(const f16x8*)&qb[(size_t)(head * 1024 + qrow) * 80 + s * 16 + h * 8];

  f32x16 ct[3] = {};
  float m_run = -INFINITY;

  issue(0);
  stage(0);
  if (tid < 64) {
    Vb0[80 * 64 + tid] = (_Float16)1.0f;
    Vb1[80 * 64 + tid] = (_Float16)1.0f;
  }
  LGKM0();
  BARRIER();
  issue(1);

  for (int kt = 0; kt < 16; ++kt) {
    const _Float16* kc = (kt & 1) ? Kb1 : Kb0;
    const _Float16* vc = (kt & 1) ? Vb1 : Vb0;

    f32x16 sc0 = {}, sc1 = {};
    __builtin_amdgcn_s_setprio(1);
    #pragma unroll
    for (int s = 0; s < 5; ++s) {
      f16x8 kf0 = *(const f16x8*)&kc[l32 * 128 + (((2 * s + h) ^ lx) << 3)];
      f16x8 kf1 = *(const f16x8*)&kc[(32 + l32) * 128 + (((2 * s + h) ^ lx) << 3)];
      sc0 = __builtin_amdgcn_mfma_f32_32x32x16_f16(kf0, qf[s], sc0, 0, 0, 0);
      sc1 = __builtin_amdgcn_mfma_f32_32x32x16_f16(kf1, qf[s], sc1, 0, 0, 0);
    }
    __builtin_amdgcn_s_setprio(0);

    // early stage+issue: ds_writes drain under the softmax window (WAR-safe per parity ledger)
    if (kt < 15) stage((kt + 1) & 1);
    if (kt < 14) issue(kt + 2);

    // max over 32 lane-local scores via v_max3 (16 ops, depth 4)
    float t0 = max3f(sc0[0], sc0[1], sc0[2]);
    float t1 = max3f(sc0[3], sc0[4], sc0[5]);
    float t2 = max3f(sc0[6], sc0[7], sc0[8]);
    float t3 = max3f(sc0[9], sc0[10], sc0[11]);
    float t4 = max3f(sc0[12], sc0[13], sc0[14]);
    float t5 = max3f(sc0[15], sc1[0], sc1[1]);
    float t6 = max3f(sc1[2], sc1[3], sc1[4]);
    float t7 = max3f(sc1[5], sc1[6], sc1[7]);
    float t8 = max3f(sc1[8], sc1[9], sc1[10]);
    float t9 = max3f(sc1[11], sc1[12], sc1[13]);
    float ta = fmaxf(sc1[14], sc1[15]);
    float u0 = max3f(t0, t1, t2);
    float u1 = max3f(t3, t4, t5);
    float u2 = max3f(t6, t7, t8);
    float tm = fmaxf(max3f(u0, u1, u2), fmaxf(t9, ta));
    tm = fmaxf(tm, __shfl_xor(tm, 32));

    // T13 defer-rescale: only rescale when the running max grew by > 8 (exp2 domain).
    if (__any(tm > m_run + 8.f)) {
      float mnew = fmaxf(m_run, tm);
      float fac = EXP2(m_run - mnew);
      #pragma unroll
      for (int dt = 0; dt < 3; ++dt)
        #pragma unroll
        for (int i = 0; i < 16; ++i) ct[dt][i] *= fac;
      m_run = mnew;
    }

    float p0[16], p1[16];
    #pragma unroll
    for (int i = 0; i < 16; ++i) p0[i] = EXP2(sc0[i] - m_run);
    #pragma unroll
    for (int i = 0; i < 16; ++i) p1[i] = EXP2(sc1[i] - m_run);

    unsigned fr[4][4];
    #define PACK4(T, PP) do {                                                \
        _Pragma("unroll")                                                    \
        for (int s16 = 0; s16 < 2; ++s16) {                                  \
          unsigned u0_ = pk2(PP[8 * s16 + 0], PP[8 * s16 + 1]);              \
          unsigned u1_ = pk2(PP[8 * s16 + 2], PP[8 * s16 + 3]);              \
          unsigned u2_ = pk2(PP[8 * s16 + 4], PP[8 * s16 + 5]);              \
          unsigned u3_ = pk2(PP[8 * s16 + 6], PP[8 * s16 + 7]);              \
          pl32swap(u0_, u2_); pl32swap(u1_, u3_);                            \
          fr[2 * (T) + s16][0] = u0_; fr[2 * (T) + s16][1] = u1_;            \
          fr[2 * (T) + s16][2] = u2_; fr[2 * (T) + s16][3] = u3_;            \
        }                                                                    \
      } while (0)
    PACK4(0, p0);
    PACK4(1, p1);

    __builtin_amdgcn_s_setprio(1);
    #pragma unroll
    for (int ss = 0; ss < 4; ++ss) {
      u32x4 fu = { fr[ss][0], fr[ss][1], fr[ss][2], fr[ss][3] };
      f16x8 pf = __builtin_bit_cast(f16x8, fu);
      #pragma unroll
      for (int dt = 0; dt < 3; ++dt) {
        f16x8 vf = *(const f16x8*)&vc[(dt * 32 + l32) * 64 + (((2 * ss + h) ^ lx) << 3)];
        ct[dt] = __builtin_amdgcn_mfma_f32_32x32x16_f16(vf, pf, ct[dt], 0, 0, 0);
      }
    }
    __builtin_amdgcn_s_setprio(0);

    if (kt < 15) {
      LGKM0();
      BARRIER();
    }
  }

  // epilogue: denominator = ct[2][8] on h=0 lanes (d=80 ones-row); broadcast to h=1
  float lsum = __shfl(ct[2][8], l32);
  float inv = 1.f / lsum;
  int sq = s0 + w * 32 + l32;
  _Float16* outp = ctxg + (size_t)(sq * 8 + bb) * 1280 + h16 * 80 + 4 * h;
  #pragma unroll
  for (int dt = 0; dt < 3; ++dt)
    #pragma unroll
    for (int rq = 0; rq < 4; ++rq) {
      if (dt == 2 && rq >= 2) continue;
      f16x4v o = { (_Float16)(ct[dt][rq * 4 + 0] * inv), (_Float16)(ct[dt][rq * 4 + 1] * inv),
                   (_Float16)(ct[dt][rq * 4 + 2] * inv), (_Float16)(ct[dt][rq * 4 + 3] * inv) };
      *(f16x4v*)&outp[dt * 32 + rq * 8] = o;
    }
}

extern "C" void kernel_launch(void* const* d_in, const int* in_sizes, int n_in,
                              void* d_out, int out_size, void* d_ws, size_t ws_size,
                              hipStream_t stream) {
  const float* x     = (const float*)d_in[0];
  const float* w_in  = (const float*)d_in[1];
  const float* b_in  = (const float*)d_in[2];
  const float* w_out = (const float*)d_in[3];
  const float* b_out = (const float*)d_in[4];
  float* out = (float*)d_out;

  char* ws = (char*)d_ws;
  size_t off = 0;
  auto carve = [&](size_t bytes) -> void* {
    void* p = ws + off;
    off += (bytes + 255) & ~(size_t)255;
    return p;
  };
  _Float16* xb     = (_Float16*)carve(8192ull * 1280 * 2);
  _Float16* w_inT  = (_Float16*)carve(3840ull * 1280 * 2);
  _Float16* w_outT = (_Float16*)carve(1280ull * 1280 * 2);
  _Float16* qb     = (_Float16*)carve(128ull * 1024 * 80 * 2);
  _Float16* kbuf   = (_Float16*)carve(128ull * 1024 * 80 * 2);
  _Float16* vbuf   = (_Float16*)carve(128ull * 1024 * 80 * 2);
  _Float16* ctxg   = (_Float16*)carve(8192ull * 1280 * 2);
  if (off > ws_size) return;

  hipFuncSetAttribute(reinterpret_cast<const void*>(&k_gemm8<8192, 3840, 1280>),
                      hipFuncAttributeMaxDynamicSharedMemorySize, 131072);
  hipFuncSetAttribute(reinterpret_cast<const void*>(&k_gemm8o<8192, 1280, 1280>),
                      hipFuncAttributeMaxDynamicSharedMemorySize, 98304);
  hipFuncSetAttribute(reinterpret_cast<const void*>(&k_attn),
                      hipFuncAttributeMaxDynamicSharedMemorySize, 57344);

  k_prep<<<8448, 256, 0, stream>>>(x, xb, w_in, w_inT, w_out, w_outT);

  k_gemm8<8192, 3840, 1280><<<480, 512, 131072, stream>>>(xb, w_inT, b_in, qb, kbuf, vbuf);
  k_attn<<<512, 512, 57344, stream>>>(qb, kbuf, vbuf, ctxg);
  k_gemm8o<8192, 1280, 1280><<<320, 512, 98304, stream>>>(ctxg, w_outT, b_out, out);
}

// Round 16
// 228.394 us; speedup vs baseline: 1.0330x; 1.0330x over previous
//
#include <hip/hip_runtime.h>

#define DEVI __device__ __forceinline__

typedef _Float16 f16x8 __attribute__((ext_vector_type(8)));
typedef _Float16 f16x4v __attribute__((ext_vector_type(4)));
typedef _Float16 f16x2 __attribute__((ext_vector_type(2)));
typedef __fp16 fp16x2 __attribute__((ext_vector_type(2)));
typedef float f32x4 __attribute__((ext_vector_type(4)));
typedef float f32x16 __attribute__((ext_vector_type(16)));
typedef unsigned u32x4 __attribute__((ext_vector_type(4)));

DEVI void gl16(const void* g, void* l) {
  __builtin_amdgcn_global_load_lds((const __attribute__((address_space(1))) void*)g,
                                   (__attribute__((address_space(3))) void*)l, 16, 0, 0);
}

#define VMCNT(N) asm volatile("s_waitcnt vmcnt(" #N ")" ::: "memory")
#define LGKM0() asm volatile("s_waitcnt lgkmcnt(0)" ::: "memory")
#define BARRIER() asm volatile("s_barrier" ::: "memory")

#if __has_builtin(__builtin_amdgcn_exp2f)
#define EXP2(x) __builtin_amdgcn_exp2f(x)
#else
#define EXP2(x) exp2f(x)
#endif

DEVI unsigned pk2(float a, float b) {
  fp16x2 t = __builtin_amdgcn_cvt_pkrtz(a, b);
  return __builtin_bit_cast(unsigned, t);
}
DEVI void pl32swap(unsigned &a, unsigned &b) {
  asm volatile("v_permlane32_swap_b32 %0, %1" : "+v"(a), "+v"(b));
}
DEVI float max3f(float a, float b, float c) {
  float d;
  asm("v_max3_f32 %0, %1, %2, %3" : "=v"(d) : "v"(a), "v"(b), "v"(c));
  return d;
}

// ---------------- fused prep: x f32->f16 + both weight transposes ----------------
// w_inT columns are PERMUTED: new col = reg*1280 + head*80 + d  (reg 0=q,1=k,2=v)
__global__ __launch_bounds__(256) void k_prep(const float* __restrict__ x, _Float16* __restrict__ xb,
                                              const float* __restrict__ w_in, _Float16* __restrict__ w_inT,
                                              const float* __restrict__ w_out, _Float16* __restrict__ w_outT) {
  __shared__ float t[32][33];
  int bid = blockIdx.x;
  int tid = threadIdx.x;
  if (bid < 2048) {
    const int n4 = 8192 * 1280 / 4;
    for (int i = bid * 256 + tid; i < n4; i += 2048 * 256) {
      float4 v = ((const float4*)x)[i];
      f16x4v h = { (_Float16)v.x, (_Float16)v.y, (_Float16)v.z, (_Float16)v.w };
      ((f16x4v*)xb)[i] = h;
    }
    return;
  }
  const float* in; _Float16* out; int R, C, tIdx; bool perm;
  if (bid < 6848) { in = w_in;  out = w_inT;  R = 1280; C = 3840; tIdx = bid - 2048; perm = true; }
  else            { in = w_out; out = w_outT; R = 1280; C = 1280; tIdx = bid - 6848; perm = false; }
  int ntc = C / 32;
  int cb = (tIdx % ntc) * 32, rb = (tIdx / ntc) * 32;
  int tx = tid & 31, ty = tid >> 5;
  #pragma unroll
  for (int i = ty; i < 32; i += 8) t[i][tx] = in[(size_t)(rb + i) * C + cb + tx];
  __syncthreads();
  #pragma unroll
  for (int i = ty; i < 32; i += 8) {
    int c = cb + i;
    if (perm) {
      int hq = c / 240, tt = c - hq * 240;
      int reg = tt / 80, d = tt - reg * 80;
      c = reg * 1280 + hq * 80 + d;
    }
    out[(size_t)c * R + rb + tx] = (_Float16)t[tx][i];
  }
}

// ================= 256x256 8-phase GEMM (qkv producer), permuted-N, row-major epilogue ========

#define MM(NLO, AF, BF) do {                                                                       \
    __builtin_amdgcn_s_setprio(1);                                                                 \
    _Pragma("unroll")                                                                              \
    for (int m_ = 0; m_ < 8; m_++) {                                                               \
      acc[m_][NLO]     = __builtin_amdgcn_mfma_f32_16x16x32_f16(AF[m_], BF[NLO],     acc[m_][NLO],     0, 0, 0); \
      acc[m_][NLO + 1] = __builtin_amdgcn_mfma_f32_16x16x32_f16(AF[m_], BF[NLO + 1], acc[m_][NLO + 1], 0, 0, 0); \
    }                                                                                              \
    __builtin_amdgcn_s_setprio(0);                                                                 \
  } while (0)

#define LDA(KT, KK, DST) do {                                                                      \
    const _Float16* bas_ = &smem[(size_t)((((KT) & 1) * 2) + wr) * 8192];                          \
    _Pragma("unroll")                                                                              \
    for (int m_ = 0; m_ < 8; m_++)                                                                 \
      DST[m_] = *(const f16x8*)&bas_[(m_ * 16 + ln) * 64 + (((((KK) * 4) + g) ^ chB) << 3)];       \
  } while (0)

#define LDB(KT, KK, DST) do {                                                                      \
    const _Float16* bas_ = &smem[32768 + (size_t)((((KT) & 1) * 2) + (wc >> 1)) * 8192];           \
    _Pragma("unroll")                                                                              \
    for (int n_ = 0; n_ < 4; n_++)                                                                 \
      DST[n_] = *(const f16x8*)&bas_[((wc & 1) * 64 + n_ * 16 + ln) * 64 + (((((KK) * 4) + g) ^ chB) << 3)]; \
  } while (0)

template<int M, int N, int K>
__global__ __launch_bounds__(512, 2) void k_gemm8(const _Float16* __restrict__ A, const _Float16* __restrict__ BT,
                                                  const float* __restrict__ bias,
                                                  _Float16* __restrict__ qo, _Float16* __restrict__ ko,
                                                  _Float16* __restrict__ vo) {
  extern __shared__ _Float16 smem[];
  constexpr int NT = K / 64;
  constexpr int NI = NT / 2;
  const int tid = threadIdx.x;
  const int w = tid >> 6, lane = tid & 63, ln = lane & 15, g = lane >> 4;
  const int wr = w >> 2, wc = w & 3;
  const int l8 = lane >> 3, l7 = lane & 7;
  const int stChunk = (l7 ^ l8) << 3;
  const int chB = ln & 7;

  constexpr int MT = M / 256;
  const int xcd = blockIdx.x & 7;
  const int i = blockIdx.x >> 3;
  const int bm0 = (xcd * (MT / 8) + (i & 3)) * 256;
  const int bn0 = (i >> 2) * 256;

  auto stgA = [&](int kt, int hh) {
    _Float16* ldsb = &smem[(size_t)((kt & 1) * 2 + hh) * 8192 + w * 1024];
    const _Float16* g0 = &A[(size_t)(bm0 + hh * 128 + w * 16 + l8) * K + kt * 64 + stChunk];
    gl16(g0, ldsb);
    gl16(g0 + (size_t)8 * K, ldsb + 512);
  };
  auto stgB = [&](int kt, int hh) {
    _Float16* ldsb = &smem[32768 + (size_t)((kt & 1) * 2 + hh) * 8192 + w * 1024];
    const _Float16* g0 = &BT[(size_t)(bn0 + hh * 128 + w * 16 + l8) * K + kt * 64 + stChunk];
    gl16(g0, ldsb);
    gl16(g0 + (size_t)8 * K, ldsb + 512);
  };

  f32x4 acc[8][4] = {};
  f16x8 a0[8], a1[8], b0[4], b1[4];

  stgB(0, 0); stgB(0, 1); stgA(0, 0); stgA(0, 1);
  stgB(1, 0); stgB(1, 1); stgA(1, 0);
  VMCNT(6);
  BARRIER();
  LDA(0, 0, a0); LDB(0, 0, b0);

  for (int it = 0; it < NI; ++it) {
    const int T0 = 2 * it, T1 = 2 * it + 1;
    const int S0 = (T0 + 2 < NT) ? T0 + 2 : 0;
    const int S1 = (T1 + 2 < NT) ? T1 + 2 : 1;
    LDB(T0, 1, b1);
    stgA(T1, 1);
    BARRIER();
    MM(0, a0, b0);
    LGKM0(); BARRIER();
    LDA(T0, 1, a1);
    stgB(S0, 0);
    BARRIER();
    MM(2, a0, b0);
    LGKM0(); BARRIER();
    stgB(S0, 1);
    BARRIER();
    MM(0, a1, b1);
    VMCNT(4);
    LGKM0(); BARRIER();
    LDA(T1, 0, a0); LDB(T1, 0, b0);
    stgA(S0, 0);
    BARRIER();
    MM(2, a1, b1);
    LGKM0(); BARRIER();
    LDB(T1, 1, b1);
    stgA(S0, 1);
    BARRIER();
    MM(0, a0, b0);
    LGKM0(); BARRIER();
    LDA(T1, 1, a1);
    stgB(S1, 0);
    BARRIER();
    MM(2, a0, b0);
    LGKM0(); BARRIER();
    stgB(S1, 1);
    BARRIER();
    MM(0, a1, b1);
    VMCNT(4);
    LGKM0(); BARRIER();
    LDA(S0, 0, a0); LDB(S0, 0, b0);
    stgA(S1, 0);
    BARRIER();
    MM(2, a1, b1);
    LGKM0(); BARRIER();
  }

  // ---- epilogue: acc -> LDS f16 [256][256]; tile purely q, k, or v; row-major stores ----
  VMCNT(0);
  BARRIER();
  _Float16* sH = smem;
  const int regn = bn0 / 1280;   // 0=q, 1=k, 2=v
  const int relb = bn0 - regn * 1280;
  #pragma unroll
  for (int n = 0; n < 4; n++) {
    int col = wc * 64 + n * 16 + ln;
    int rel = relb + col;
    int h = rel / 80, d = rel - h * 80;
    float bv = bias[h * 240 + regn * 80 + d];
    float scl = (regn == 0) ? (0.11180339887498948f * 1.4426950408889634f) : 1.0f;
    #pragma unroll
    for (int m = 0; m < 8; m++) {
      #pragma unroll
      for (int r = 0; r < 4; r++) {
        int row = wr * 128 + m * 16 + 4 * g + r;
        sH[row * 256 + col] = (_Float16)((acc[m][n][r] + bv) * scl);
      }
    }
  }
  LGKM0();
  BARRIER();
  _Float16* dst = (regn == 0) ? qo : (regn == 1) ? ko : vo;   // all [head][1024][80]
  #pragma unroll
  for (int i2 = 0; i2 < 16; i2++) {
    int id = tid + 512 * i2;
    int row = id >> 5, c8 = id & 31;
    f16x8 v = *(const f16x8*)&sH[row * 256 + c8 * 8];
    int rel = relb + c8 * 8;
    int h = rel / 80, d0 = rel - h * 80;
    int grow = bm0 + row;
    *(f16x8*)&dst[(size_t)(((grow & 7) * 16 + h) * 1024 + (grow >> 3)) * 80 + d0] = v;
  }
}

// ================= 128x256 8-phase GEMM (out_proj): C[M,N] f32 = A*BT^T + bias =================

#define MMo(NLO, AF, BF) do {                                                                      \
    __builtin_amdgcn_s_setprio(1);                                                                 \
    _Pragma("unroll")                                                                              \
    for (int m_ = 0; m_ < 4; m_++) {                                                               \
      acc[m_][NLO]     = __builtin_amdgcn_mfma_f32_16x16x32_f16(AF[m_], BF[NLO],     acc[m_][NLO],     0, 0, 0); \
      acc[m_][NLO + 1] = __builtin_amdgcn_mfma_f32_16x16x32_f16(AF[m_], BF[NLO + 1], acc[m_][NLO + 1], 0, 0, 0); \
    }                                                                                              \
    __builtin_amdgcn_s_setprio(0);                                                                 \
  } while (0)

#define LDAo(KT, KK, DST) do {                                                                     \
    const _Float16* bas_ = &smem[(size_t)((KT) & 1) * 8192];                                       \
    _Pragma("unroll")                                                                              \
    for (int m_ = 0; m_ < 4; m_++)                                                                 \
      DST[m_] = *(const f16x8*)&bas_[(wr * 64 + m_ * 16 + ln) * 64 + (((((KK) * 4) + g) ^ chB) << 3)]; \
  } while (0)

#define LDBo(KT, KK, DST) do {                                                                     \
    const _Float16* bas_ = &smem[16384 + (size_t)(((KT) & 1) * 2 + (wc >> 1)) * 8192];             \
    _Pragma("unroll")                                                                              \
    for (int n_ = 0; n_ < 4; n_++)                                                                 \
      DST[n_] = *(const f16x8*)&bas_[((wc & 1) * 64 + n_ * 16 + ln) * 64 + (((((KK) * 4) + g) ^ chB) << 3)]; \
  } while (0)

template<int M, int N, int K>
__global__ __launch_bounds__(512, 2) void k_gemm8o(const _Float16* __restrict__ A, const _Float16* __restrict__ BT,
                                                   const float* __restrict__ bias, float* __restrict__ outF) {
  extern __shared__ _Float16 smem[];
  constexpr int NT = K / 64;     // 20
  constexpr int NI = NT / 2;     // 10
  const int tid = threadIdx.x;
  const int w = tid >> 6, lane = tid & 63, ln = lane & 15, g = lane >> 4;
  const int wr = w >> 2, wc = w & 3;
  const int l8 = lane >> 3, l7 = lane & 7;
  const int stChunk = (l7 ^ l8) << 3;
  const int chB = ln & 7;

  const int xcd = blockIdx.x & 7;
  const int i = blockIdx.x >> 3;            // 0..39
  const int bm0 = (xcd * 8 + (i & 7)) * 128;
  const int bn0 = (i >> 3) * 256;

  auto stgA = [&](int kt) {
    _Float16* ldsb = &smem[(size_t)(kt & 1) * 8192 + w * 1024];
    const _Float16* g0 = &A[(size_t)(bm0 + w * 16 + l8) * K + kt * 64 + stChunk];
    gl16(g0, ldsb);
    gl16(g0 + (size_t)8 * K, ldsb + 512);
  };
  auto stgB = [&](int kt, int hh) {
    _Float16* ldsb = &smem[16384 + (size_t)((kt & 1) * 2 + hh) * 8192 + w * 1024];
    const _Float16* g0 = &BT[(size_t)(bn0 + hh * 128 + w * 16 + l8) * K + kt * 64 + stChunk];
    gl16(g0, ldsb);
    gl16(g0 + (size_t)8 * K, ldsb + 512);
  };

  f32x4 acc[4][4] = {};
  f16x8 a0[4], a1[4], b0[4], b1[4];

  stgB(0, 0); stgB(0, 1); stgA(0);
  stgB(1, 0); stgB(1, 1); stgA(1);
  VMCNT(6);
  BARRIER();
  LDAo(0, 0, a0); LDBo(0, 0, b0);

  for (int it = 0; it < NI; ++it) {
    const int T0 = 2 * it, T1 = 2 * it + 1;
    const int S0 = (T0 + 2 < NT) ? T0 + 2 : 0;
    const int S1 = (T1 + 2 < NT) ? T1 + 2 : 1;
    LDBo(T0, 1, b1);
    BARRIER(); MMo(0, a0, b0); LGKM0(); BARRIER();
    LDAo(T0, 1, a1);
    stgB(S0, 0);
    BARRIER(); MMo(2, a0, b0); LGKM0(); BARRIER();
    stgB(S0, 1);
    BARRIER(); MMo(0, a1, b1); VMCNT(4); LGKM0(); BARRIER();
    LDAo(T1, 0, a0); LDBo(T1, 0, b0);
    stgA(S0);
    BARRIER(); MMo(2, a1, b1); LGKM0(); BARRIER();
    LDBo(T1, 1, b1);
    BARRIER(); MMo(0, a0, b0); LGKM0(); BARRIER();
    LDAo(T1, 1, a1);
    stgB(S1, 0);
    BARRIER(); MMo(2, a0, b0); LGKM0(); BARRIER();
    stgB(S1, 1);
    BARRIER(); MMo(0, a1, b1); VMCNT(4); LGKM0(); BARRIER();
    LDAo(S0, 0, a0); LDBo(S0, 0, b0);
    stgA(S1);
    BARRIER(); MMo(2, a1, b1); LGKM0(); BARRIER();
  }

  VMCNT(0);
  #pragma unroll
  for (int n = 0; n < 4; n++) {
    int col = bn0 + wc * 64 + n * 16 + ln;
    float bv = bias[col];
    #pragma unroll
    for (int m = 0; m < 4; m++) {
      int rbase = bm0 + wr * 64 + m * 16 + 4 * g;
      #pragma unroll
      for (int r = 0; r < 4; r++)
        outF[(size_t)(rbase + r) * N + col] = acc[m][n][r] + bv;
    }
  }
}

// ---------------- flash attention: QBLK=256, 8 waves x 32 q-rows, in-register softmax ----------------
// qb/kb/vb: [head][1024][80] f16 (q pre-scaled by log2e/sqrt(80)); V transposed during staging
// via quad-chunks + b64 writes. V^T row 80 = ones -> ct[2][8] accumulates the softmax denominator.
__global__ __launch_bounds__(512, 2) void k_attn(const _Float16* __restrict__ qb, const _Float16* __restrict__ kb,
                                                 const _Float16* __restrict__ vb, _Float16* __restrict__ ctxg) {
  extern __shared__ _Float16 smem[];
  _Float16* Kb0 = smem;                    // [64][128] swizzled
  _Float16* Kb1 = smem + 8192;
  _Float16* Vb0 = smem + 16384;            // [96][64] swizzled; rows 81..95 garbage (ignored)
  _Float16* Vb1 = smem + 16384 + 6144;

  const int tid = threadIdx.x;
  const int w = tid >> 6, lane = tid & 63;
  const int l32 = lane & 31, h = lane >> 5;
  const int lx = l32 & 7;
  const int xcd = blockIdx.x & 7;
  const int j = blockIdx.x >> 3;
  const int head = xcd + 8 * (j & 15);
  const int s0 = (j >> 4) * 256;
  const int bb = head >> 4, h16 = head & 15;
  const size_t hbase = (size_t)head * 81920;

  const int cA = tid;
  const int cB = (tid < 128) ? tid + 512 : tid;
  const int sA = cA & 63, dA = cA >> 6;
  const int sB = cB & 63, dB = cB >> 6;
  const _Float16* kGA = kb + hbase + sA * 80 + dA * 8;
  const _Float16* kGB = kb + hbase + sB * 80 + dB * 8;
  const int kOA = sA * 128 + ((dA ^ (sA & 7)) << 3);
  const int kOB = sB * 128 + ((dB ^ (sB & 7)) << 3);

  const int s4 = tid & 15, dc = tid >> 4;
  const _Float16* vG = vb + hbase + (s4 * 4) * 80 + dc * 8;

  uint4 krA, krB, vq0, vq1, vq2, vq3;
  auto issue = [&](int kt) {
    krA = *(const uint4*)(kGA + kt * 5120);
    krB = *(const uint4*)(kGB + kt * 5120);
    if (tid < 160) {
      const _Float16* p = vG + kt * 5120;
      vq0 = *(const uint4*)(p);
      vq1 = *(const uint4*)(p + 80);
      vq2 = *(const uint4*)(p + 160);
      vq3 = *(const uint4*)(p + 240);
    }
  };
  auto stage = [&](int b) {
    _Float16* kd = b ? Kb1 : Kb0;
    _Float16* vd = b ? Vb1 : Vb0;
    *(uint4*)(kd + kOA) = krA;
    *(uint4*)(kd + kOB) = krB;
    if (tid < 160) {
      const unsigned* w0 = (const unsigned*)&vq0;
      const unsigned* w1 = (const unsigned*)&vq1;
      const unsigned* w2 = (const unsigned*)&vq2;
      const unsigned* w3 = (const unsigned*)&vq3;
      #pragma unroll
      for (int jj = 0; jj < 8; ++jj) {
        int jw = jj >> 1;
        unsigned lo, hi;
        if (jj & 1) {
          lo = (w0[jw] >> 16) | (w1[jw] & 0xffff0000u);
          hi = (w2[jw] >> 16) | (w3[jw] & 0xffff0000u);
        } else {
          lo = (w0[jw] & 0xffffu) | (w1[jw] << 16);
          hi = (w2[jw] & 0xffffu) | (w3[jw] << 16);
        }
        unsigned long long u = (unsigned long long)lo | ((unsigned long long)hi << 32);
        int d = dc * 8 + jj;
        *(unsigned long long*)(vd + d * 64 + (((s4 >> 1) ^ jj) << 3) + ((s4 & 1) << 2)) = u;
      }
    }
  };

  const int qrow = s0 + w * 32 + l32;
  f16x8 qf[5];
  #pragma unroll
  for (int s = 0; s < 5; s++)
    qf[s] = *(const f16x8*)&qb[(size_t)(head * 1024 + qrow) * 80 + s * 16 + h * 8];

  f32x16 ct[3] = {};
  float m_run = -INFINITY;

  issue(0);
  stage(0);
  if (tid < 64) {
    Vb0[80 * 64 + tid] = (_Float16)1.0f;
    Vb1[80 * 64 + tid] = (_Float16)1.0f;
  }
  LGKM0();
  BARRIER();
  issue(1);

  for (int kt = 0; kt < 16; ++kt) {
    const _Float16* kc = (kt & 1) ? Kb1 : Kb0;
    const _Float16* vc = (kt & 1) ? Vb1 : Vb0;

    f32x16 sc0 = {}, sc1 = {};
    __builtin_amdgcn_s_setprio(1);
    #pragma unroll
    for (int s = 0; s < 5; ++s) {
      f16x8 kf0 = *(const f16x8*)&kc[l32 * 128 + (((2 * s + h) ^ lx) << 3)];
      f16x8 kf1 = *(const f16x8*)&kc[(32 + l32) * 128 + (((2 * s + h) ^ lx) << 3)];
      sc0 = __builtin_amdgcn_mfma_f32_32x32x16_f16(kf0, qf[s], sc0, 0, 0, 0);
      sc1 = __builtin_amdgcn_mfma_f32_32x32x16_f16(kf1, qf[s], sc1, 0, 0, 0);
    }
    __builtin_amdgcn_s_setprio(0);

    // early stage+issue: ds_writes drain under the softmax window (WAR-safe per parity ledger)
    if (kt < 15) stage((kt + 1) & 1);
    if (kt < 14) issue(kt + 2);

    // max over 32 lane-local scores via v_max3 (16 ops, depth 4)
    float t0 = max3f(sc0[0], sc0[1], sc0[2]);
    float t1 = max3f(sc0[3], sc0[4], sc0[5]);
    float t2 = max3f(sc0[6], sc0[7], sc0[8]);
    float t3 = max3f(sc0[9], sc0[10], sc0[11]);
    float t4 = max3f(sc0[12], sc0[13], sc0[14]);
    float t5 = max3f(sc0[15], sc1[0], sc1[1]);
    float t6 = max3f(sc1[2], sc1[3], sc1[4]);
    float t7 = max3f(sc1[5], sc1[6], sc1[7]);
    float t8 = max3f(sc1[8], sc1[9], sc1[10]);
    float t9 = max3f(sc1[11], sc1[12], sc1[13]);
    float ta = fmaxf(sc1[14], sc1[15]);
    float u0 = max3f(t0, t1, t2);
    float u1 = max3f(t3, t4, t5);
    float u2 = max3f(t6, t7, t8);
    float tm = fmaxf(max3f(u0, u1, u2), fmaxf(t9, ta));
    tm = fmaxf(tm, __shfl_xor(tm, 32));

    // T13 defer-rescale: only rescale when the running max grew by > 8 (exp2 domain).
    if (__any(tm > m_run + 8.f)) {
      float mnew = fmaxf(m_run, tm);
      float fac = EXP2(m_run - mnew);
      #pragma unroll
      for (int dt = 0; dt < 3; ++dt)
        #pragma unroll
        for (int i = 0; i < 16; ++i) ct[dt][i] *= fac;
      m_run = mnew;
    }

    float p0[16], p1[16];
    #pragma unroll
    for (int i = 0; i < 16; ++i) p0[i] = EXP2(sc0[i] - m_run);
    #pragma unroll
    for (int i = 0; i < 16; ++i) p1[i] = EXP2(sc1[i] - m_run);

    unsigned fr[4][4];
    #define PACK4(T, PP) do {                                                \
        _Pragma("unroll")                                                    \
        for (int s16 = 0; s16 < 2; ++s16) {                                  \
          unsigned u0_ = pk2(PP[8 * s16 + 0], PP[8 * s16 + 1]);              \
          unsigned u1_ = pk2(PP[8 * s16 + 2], PP[8 * s16 + 3]);              \
          unsigned u2_ = pk2(PP[8 * s16 + 4], PP[8 * s16 + 5]);              \
          unsigned u3_ = pk2(PP[8 * s16 + 6], PP[8 * s16 + 7]);              \
          pl32swap(u0_, u2_); pl32swap(u1_, u3_);                            \
          fr[2 * (T) + s16][0] = u0_; fr[2 * (T) + s16][1] = u1_;            \
          fr[2 * (T) + s16][2] = u2_; fr[2 * (T) + s16][3] = u3_;            \
        }                                                                    \
      } while (0)
    PACK4(0, p0);
    PACK4(1, p1);

    __builtin_amdgcn_s_setprio(1);
    #pragma unroll
    for (int ss = 0; ss < 4; ++ss) {
      u32x4 fu = { fr[ss][0], fr[ss][1], fr[ss][2], fr[ss][3] };
      f16x8 pf = __builtin_bit_cast(f16x8, fu);
      #pragma unroll
      for (int dt = 0; dt < 3; ++dt) {
        f16x8 vf = *(const f16x8*)&vc[(dt * 32 + l32) * 64 + (((2 * ss + h) ^ lx) << 3)];
        ct[dt] = __builtin_amdgcn_mfma_f32_32x32x16_f16(vf, pf, ct[dt], 0, 0, 0);
      }
    }
    __builtin_amdgcn_s_setprio(0);

    if (kt < 15) {
      LGKM0();
      BARRIER();
    }
  }

  // epilogue: denominator = ct[2][8] on h=0 lanes (d=80 ones-row); broadcast to h=1
  float lsum = __shfl(ct[2][8], l32);
  float inv = 1.f / lsum;
  int sq = s0 + w * 32 + l32;
  _Float16* outp = ctxg + (size_t)(sq * 8 + bb) * 1280 + h16 * 80 + 4 * h;
  #pragma unroll
  for (int dt = 0; dt < 3; ++dt)
    #pragma unroll
    for (int rq = 0; rq < 4; ++rq) {
      if (dt == 2 && rq >= 2) continue;
      f16x4v o = { (_Float16)(ct[dt][rq * 4 + 0] * inv), (_Float16)(ct[dt][rq * 4 + 1] * inv),
                   (_Float16)(ct[dt][rq * 4 + 2] * inv), (_Float16)(ct[dt][rq * 4 + 3] * inv) };
      *(f16x4v*)&outp[dt * 32 + rq * 8] = o;
    }
}

extern "C" void kernel_launch(void* const* d_in, const int* in_sizes, int n_in,
                              void* d_out, int out_size, void* d_ws, size_t ws_size,
                              hipStream_t stream) {
  const float* x     = (const float*)d_in[0];
  const float* w_in  = (const float*)d_in[1];
  const float* b_in  = (const float*)d_in[2];
  const float* w_out = (const float*)d_in[3];
  const float* b_out = (const float*)d_in[4];
  float* out = (float*)d_out;

  char* ws = (char*)d_ws;
  size_t off = 0;
  auto carve = [&](size_t bytes) -> void* {
    void* p = ws + off;
    off += (bytes + 255) & ~(size_t)255;
    return p;
  };
  _Float16* xb     = (_Float16*)carve(8192ull * 1280 * 2);
  _Float16* w_inT  = (_Float16*)carve(3840ull * 1280 * 2);
  _Float16* w_outT = (_Float16*)carve(1280ull * 1280 * 2);
  _Float16* qb     = (_Float16*)carve(128ull * 1024 * 80 * 2);
  _Float16* kbuf   = (_Float16*)carve(128ull * 1024 * 80 * 2);
  _Float16* vbuf   = (_Float16*)carve(128ull * 1024 * 80 * 2);
  _Float16* ctxg   = (_Float16*)carve(8192ull * 1280 * 2);
  if (off > ws_size) return;

  hipFuncSetAttribute(reinterpret_cast<const void*>(&k_gemm8<8192, 3840, 1280>),
                      hipFuncAttributeMaxDynamicSharedMemorySize, 131072);
  hipFuncSetAttribute(reinterpret_cast<const void*>(&k_gemm8o<8192, 1280, 1280>),
                      hipFuncAttributeMaxDynamicSharedMemorySize, 98304);
  hipFuncSetAttribute(reinterpret_cast<const void*>(&k_attn),
                      hipFuncAttributeMaxDynamicSharedMemorySize, 57344);

  k_prep<<<8448, 256, 0, stream>>>(x, xb, w_in, w_inT, w_out, w_outT);

  k_gemm8<8192, 3840, 1280><<<480, 512, 131072, stream>>>(xb, w_inT, b_in, qb, kbuf, vbuf);
  k_attn<<<512, 512, 57344, stream>>>(qb, kbuf, vbuf, ctxg);
  k_gemm8o<8192, 1280, 1280><<<320, 512, 98304, stream>>>(ctxg, w_outT, b_out, out);
}